// Round 6
// baseline (88.687 us; speedup 1.0000x reference)
//
#include <hip/hip_runtime.h>
#include <hip/hip_bf16.h>
#include <stdint.h>
#include <stddef.h>

typedef __bf16 bf16_t;
typedef __attribute__((ext_vector_type(8))) __bf16 bf16x8;
typedef __attribute__((ext_vector_type(4))) float f32x4;

#define TOK 2048      // N*M tokens
#define DMODEL 1024
#define NHEAD 16

__device__ __forceinline__ void gload_lds16(const void* g, void* l) {
  __builtin_amdgcn_global_load_lds(
      (const __attribute__((address_space(1))) void*)g,
      (__attribute__((address_space(3))) void*)l, 16, 0, 0);
}

// ---------------- fp32 -> bf16 convert (weights only) ----------------
struct CvtArgs {
  const float* src[4];
  bf16_t* dst[4];
};

__global__ __launch_bounds__(256) void cvt_kernel(CvtArgs a) {
  int arr = blockIdx.y;
  int i = (blockIdx.x * 256 + threadIdx.x) * 8;
  const float* s = a.src[arr];
  bf16_t* d = a.dst[arr];
  f32x4 x0 = *(const f32x4*)(s + i);
  f32x4 x1 = *(const f32x4*)(s + i + 4);
  bf16x8 o;
  o[0] = (bf16_t)x0[0]; o[1] = (bf16_t)x0[1]; o[2] = (bf16_t)x0[2]; o[3] = (bf16_t)x0[3];
  o[4] = (bf16_t)x1[0]; o[5] = (bf16_t)x1[1]; o[6] = (bf16_t)x1[2]; o[7] = (bf16_t)x1[3];
  *(bf16x8*)(d + i) = o;
}

// =============== 64x64-tile GEMM, BK=64, 3-buffer counted-vmcnt pipeline ===============
// C[row][col] = sum_k A[row][k] * W[col][k] + bias[col]   (M=2048, N=K=1024)
// AF32: A fp32, reg-loaded 1 step ahead, cvt->ds_write into padded LDS (stride 72).
// !AF32: A bf16 via global_load_lds, linear XOR-swizzled (both-sides).
// W always via global_load_lds, XOR chunk swizzle.
struct GArgs {
  const void* A[3];
  const bf16_t* W[3];
  const float* bias[3];
  void* C[3];
};

template <bool AF32, typename CT>
__global__ __launch_bounds__(256, 3) void gemm3(GArgs g) {
  constexpr int K = DMODEL, N = DMODEL;
  // XCD-locality decode: z-major chunks of 512; within chunk xcd = i&7 owns
  // a contiguous 4-strip of bm x all 16 bn  (per-XCD WS: A-strip + W_z <= L2)
  const int i = blockIdx.x;
  const int xcd = i & 7, slot = i >> 3;
  const int z = slot >> 6;             // 0..2 for the 1536-grid, 0 for 512-grid
  const int s = slot & 63;
  const int bm = (xcd * 4 + (s >> 4)) * 64;
  const int bn = (s & 15) * 64;

  const bf16_t* __restrict__ W = g.W[z];
  const float* __restrict__ bias = g.bias[z];
  CT* __restrict__ C = (CT*)g.C[z];

  constexpr int ALD = AF32 ? 72 : 64;
  __shared__ alignas(16) bf16_t As[3][64 * ALD];
  __shared__ alignas(16) bf16_t Bs[3][64 * 64];

  const int tid = threadIdx.x;
  const int wv = tid >> 6, lane = tid & 63;
  const int wr = (wv >> 1) * 32, wc = (wv & 1) * 32;
  const int lm = lane & 15, lch = lane >> 4;
  const int cr4 = (lane >> 4) * 4;

  // gload staging coords (W always; A when !AF32)
  const int srow = wv * 8 + (lane >> 3);
  const int sc = (lane & 7) ^ (lane >> 3);
  const bf16_t* Wbase = W + (size_t)(bn + srow) * K + sc * 8;
  const bf16_t* Abase = AF32 ? nullptr
                             : ((const bf16_t*)g.A[z] + (size_t)(bm + srow) * K + sc * 8);
  const int ldsoff0 = (wv * 8) * 64;
  const int ldsoff1 = (wv * 8 + 32) * 64;

  // AF32 reg-staging coords
  const int trow = tid >> 2, tcol = (tid & 3) * 16;
  const float* Af = AF32 ? ((const float*)g.A[z] + (size_t)(bm + trow) * K + tcol) : nullptr;

  f32x4 acc[2][2] = {};
  constexpr int nt = K / 64;   // 16
  f32x4 hA0, hA1, hA2, hA3;    // AF32: held fp32 A-tile (written next step)

  // ---- prologue ----
  if (AF32) {
    gload_lds16(Wbase, &Bs[0][ldsoff0]);
    gload_lds16(Wbase + (size_t)32 * K, &Bs[0][ldsoff1]);
    gload_lds16(Wbase + 64, &Bs[1][ldsoff0]);
    gload_lds16(Wbase + 64 + (size_t)32 * K, &Bs[1][ldsoff1]);
    hA0 = *(const f32x4*)(Af);     hA1 = *(const f32x4*)(Af + 4);
    hA2 = *(const f32x4*)(Af + 8); hA3 = *(const f32x4*)(Af + 12);
    {  // cvt + write tile 0 (implicit wait drains W0 too)
      bf16x8 c0, c1;
#pragma unroll
      for (int e = 0; e < 4; ++e) {
        c0[e] = (bf16_t)hA0[e]; c0[e + 4] = (bf16_t)hA1[e];
        c1[e] = (bf16_t)hA2[e]; c1[e + 4] = (bf16_t)hA3[e];
      }
      *(bf16x8*)&As[0][trow * ALD + tcol] = c0;
      *(bf16x8*)&As[0][trow * ALD + tcol + 8] = c1;
    }
    // load tile 1 fp32 into held regs
    hA0 = *(const f32x4*)(Af + 64);     hA1 = *(const f32x4*)(Af + 68);
    hA2 = *(const f32x4*)(Af + 72);     hA3 = *(const f32x4*)(Af + 76);
    asm volatile("s_waitcnt lgkmcnt(0)" ::: "memory");
    __builtin_amdgcn_sched_barrier(0);
    __builtin_amdgcn_s_barrier();
  } else {
#pragma unroll
    for (int t0 = 0; t0 < 2; ++t0) {
      gload_lds16(Abase + t0 * 64, &As[t0][ldsoff0]);
      gload_lds16(Abase + t0 * 64 + (size_t)32 * K, &As[t0][ldsoff1]);
      gload_lds16(Wbase + t0 * 64, &Bs[t0][ldsoff0]);
      gload_lds16(Wbase + t0 * 64 + (size_t)32 * K, &Bs[t0][ldsoff1]);
    }
  }

  for (int t = 0; t < nt; ++t) {
    // ---- wait tile t staged; leave tile t+1's loads in flight ----
    if (t + 1 < nt) {
      if (AF32) asm volatile("s_waitcnt vmcnt(6) lgkmcnt(0)" ::: "memory");
      else      asm volatile("s_waitcnt vmcnt(4) lgkmcnt(0)" ::: "memory");
    } else {
      asm volatile("s_waitcnt vmcnt(0) lgkmcnt(0)" ::: "memory");
    }
    __builtin_amdgcn_sched_barrier(0);
    __builtin_amdgcn_s_barrier();
    __builtin_amdgcn_sched_barrier(0);

    // ---- issue stage of tile t+2 ----
    if (t + 2 < nt) {
      const int b2 = (t + 2) % 3;
      gload_lds16(Wbase + (t + 2) * 64, &Bs[b2][ldsoff0]);
      gload_lds16(Wbase + (t + 2) * 64 + (size_t)32 * K, &Bs[b2][ldsoff1]);
      if (!AF32) {
        gload_lds16(Abase + (t + 2) * 64, &As[b2][ldsoff0]);
        gload_lds16(Abase + (t + 2) * 64 + (size_t)32 * K, &As[b2][ldsoff1]);
      }
    }
    f32x4 nA0, nA1, nA2, nA3;
    if (AF32 && t + 2 < nt) {
      const float* ap = Af + (t + 2) * 64;
      nA0 = *(const f32x4*)(ap);      nA1 = *(const f32x4*)(ap + 4);
      nA2 = *(const f32x4*)(ap + 8);  nA3 = *(const f32x4*)(ap + 12);
    }
    // ---- AF32: cvt held tile t+1, ds_write into As[(t+1)%3] ----
    if (AF32 && t + 1 < nt) {
      const int b1 = (t + 1) % 3;
      bf16x8 c0, c1;
#pragma unroll
      for (int e = 0; e < 4; ++e) {
        c0[e] = (bf16_t)hA0[e]; c0[e + 4] = (bf16_t)hA1[e];
        c1[e] = (bf16_t)hA2[e]; c1[e + 4] = (bf16_t)hA3[e];
      }
      *(bf16x8*)&As[b1][trow * ALD + tcol] = c0;
      *(bf16x8*)&As[b1][trow * ALD + tcol + 8] = c1;
    }

    // ---- frag reads, pinned in two kk-groups ----
    const int b = t % 3;
    bf16x8 fa[2][2], fb[2][2];
#pragma unroll
    for (int kk = 0; kk < 2; ++kk) {
#pragma unroll
      for (int ii = 0; ii < 2; ++ii) {
        const int ra = wr + ii * 16 + lm;
        if (AF32) {
          fa[kk][ii] = *(const bf16x8*)&As[b][ra * ALD + kk * 32 + lch * 8];
        } else {
          fa[kk][ii] = *(const bf16x8*)&As[b][ra * 64 + (((kk * 4 + lch) ^ (ra & 7)) * 8)];
        }
        const int rb = wc + ii * 16 + lm;
        fb[kk][ii] = *(const bf16x8*)&Bs[b][rb * 64 + (((kk * 4 + lch) ^ (rb & 7)) * 8)];
      }
      __builtin_amdgcn_sched_barrier(0);   // pin kk0-group before kk1-group
    }

    // ---- MFMA: kk0 while kk1 frags land ----
    asm volatile("s_waitcnt lgkmcnt(4)" ::: "memory");
    __builtin_amdgcn_sched_barrier(0);
    __builtin_amdgcn_s_setprio(1);
#pragma unroll
    for (int ii = 0; ii < 2; ++ii)
#pragma unroll
      for (int jj = 0; jj < 2; ++jj)
        acc[ii][jj] = __builtin_amdgcn_mfma_f32_16x16x32_bf16(fa[0][ii], fb[0][jj], acc[ii][jj], 0, 0, 0);
    __builtin_amdgcn_s_setprio(0);
    asm volatile("s_waitcnt lgkmcnt(0)" ::: "memory");
    __builtin_amdgcn_sched_barrier(0);
    __builtin_amdgcn_s_setprio(1);
#pragma unroll
    for (int ii = 0; ii < 2; ++ii)
#pragma unroll
      for (int jj = 0; jj < 2; ++jj)
        acc[ii][jj] = __builtin_amdgcn_mfma_f32_16x16x32_bf16(fa[1][ii], fb[1][jj], acc[ii][jj], 0, 0, 0);
    __builtin_amdgcn_s_setprio(0);

    if (AF32) { hA0 = nA0; hA1 = nA1; hA2 = nA2; hA3 = nA3; }
  }

  // ---- epilogue: bias + store ----
#pragma unroll
  for (int ii = 0; ii < 2; ++ii)
#pragma unroll
    for (int jj = 0; jj < 2; ++jj) {
      const int col = bn + wc + jj * 16 + lm;
      const float bvv = bias[col];
#pragma unroll
      for (int r = 0; r < 4; ++r) {
        const int row = bm + wr + ii * 16 + cr4 + r;
        C[(size_t)row * N + col] = (CT)(acc[ii][jj][r] + bvv);
      }
    }
}

// ---------------- per-(token,head) channel attention ----------------
__global__ __launch_bounds__(256) void attn_kernel(
    const bf16_t* __restrict__ q, const bf16_t* __restrict__ k,
    const bf16_t* __restrict__ v, bf16_t* __restrict__ ctx) {
  __shared__ float kv[4][64][2];
  const int wv = threadIdx.x >> 6, lane = threadIdx.x & 63;
  const int pair = blockIdx.x * 4 + wv;          // t*16 + h
  const size_t base = (size_t)pair * 64;
  float qd = (float)q[base + lane];
  float kd = (float)k[base + lane];
  float vd = (float)v[base + lane];
  kv[wv][lane][0] = kd;
  kv[wv][lane][1] = vd;
  __syncthreads();

  float kmax = kd, kmin = kd;
#pragma unroll
  for (int off = 32; off; off >>= 1) {
    kmax = fmaxf(kmax, __shfl_xor(kmax, off));
    kmin = fminf(kmin, __shfl_xor(kmin, off));
  }
  const float sc = 0.125f * 1.44269504088896341f;  // (1/sqrt(64)) * log2(e)
  float a = (float)qd * sc;
  float m = fmaxf(a * kmax, a * kmin);
  float sum = 0.f, accv = 0.f;
#pragma unroll 8
  for (int j = 0; j < 64; ++j) {
    float kj = kv[wv][j][0];
    float vj = kv[wv][j][1];
    float e = exp2f(fmaf(a, kj, -m));
    sum += e;
    accv = fmaf(e, vj, accv);
  }
  ctx[base + lane] = (bf16_t)(accv * __builtin_amdgcn_rcpf(sum));
}

// ---------------- launch ----------------
extern "C" void kernel_launch(void* const* d_in, const int* in_sizes, int n_in,
                              void* d_out, int out_size, void* d_ws, size_t ws_size,
                              hipStream_t stream) {
  const float* query = (const float*)d_in[0];
  const float* key   = (const float*)d_in[1];
  const float* value = (const float*)d_in[2];
  const float* Wq = (const float*)d_in[3];
  const float* bq = (const float*)d_in[4];
  const float* Wk = (const float*)d_in[5];
  const float* bk = (const float*)d_in[6];
  const float* Wv = (const float*)d_in[7];
  const float* bv = (const float*)d_in[8];
  const float* Wo = (const float*)d_in[9];
  const float* bo = (const float*)d_in[10];
  float* out = (float*)d_out;

  const size_t XE = (size_t)TOK * DMODEL;
  const size_t WE = (size_t)DMODEL * DMODEL;

  char* ws = (char*)d_ws;
  size_t off = 0;
  bf16_t* wb[4];
  for (int i = 0; i < 4; ++i) { wb[i] = (bf16_t*)(ws + off); off += WE * 2; }
  bf16_t* pb[3];   // projected q,k,v bf16
  for (int i = 0; i < 3; ++i) { pb[i] = (bf16_t*)(ws + off); off += XE * 2; }
  bf16_t* ctxb = (bf16_t*)(ws + off); off += XE * 2;

  // 1) convert weights to bf16
  CvtArgs ca;
  ca.src[0] = Wq; ca.src[1] = Wk; ca.src[2] = Wv; ca.src[3] = Wo;
  ca.dst[0] = wb[0]; ca.dst[1] = wb[1]; ca.dst[2] = wb[2]; ca.dst[3] = wb[3];
  cvt_kernel<<<dim3((unsigned)(WE / (256 * 8)), 4), 256, 0, stream>>>(ca);

  // 2) QKV projection (fp32 A folded into staging): 1536 blocks
  GArgs g1;
  g1.A[0] = query; g1.A[1] = key; g1.A[2] = value;
  g1.W[0] = wb[0]; g1.W[1] = wb[1]; g1.W[2] = wb[2];
  g1.bias[0] = bq; g1.bias[1] = bk; g1.bias[2] = bv;
  g1.C[0] = pb[0]; g1.C[1] = pb[1]; g1.C[2] = pb[2];
  gemm3<true, bf16_t><<<dim3(1536), 256, 0, stream>>>(g1);

  // 3) per-(token,head) channel attention
  attn_kernel<<<dim3(TOK * NHEAD / 4), 256, 0, stream>>>(pb[0], pb[1], pb[2], ctxb);

  // 4) output projection -> fp32 out: 512 blocks
  GArgs g2;
  g2.A[0] = ctxb; g2.W[0] = wb[3]; g2.bias[0] = bo; g2.C[0] = out;
  g2.A[1] = ctxb; g2.W[1] = wb[3]; g2.bias[1] = bo; g2.C[1] = out;
  g2.A[2] = ctxb; g2.W[2] = wb[3]; g2.bias[2] = bo; g2.C[2] = out;
  gemm3<false, float><<<dim3(512), 256, 0, stream>>>(g2);
}